// Round 7
// baseline (176.179 us; speedup 1.0000x reference)
//
#include <hip/hip_runtime.h>

#define BN 1024
#define NV 6890
#define NBETA 10
#define PB 207            // pose basis = 9*(J-1)
#define N3 20670          // NV*3
#define NCOL 20736        // 108*192 padded GEMM columns
#define NCHUNK 7          // K = 224 = 207 pose + 10 betas + 1 template + 6 zero
#define BT 32             // batches per k_vert block

typedef __bf16 bf16x8 __attribute__((ext_vector_type(8)));
typedef float  f32x4  __attribute__((ext_vector_type(4)));

__device__ __constant__ int c_par[24] = {-1,0,0,0,1,2,3,4,5,6,7,8,9,9,9,12,13,14,16,17,18,19,20,21};

__device__ inline unsigned short f2bf(float f) {
    unsigned u = __float_as_uint(f);
    u += 0x7fff + ((u >> 16) & 1);          // RNE
    return (unsigned short)(u >> 16);
}

__device__ inline void dma16(const void* g, void* l) {
    __builtin_amdgcn_global_load_lds(
        (const __attribute__((address_space(1))) unsigned int*)g,
        (__attribute__((address_space(3))) unsigned int*)l, 16, 0, 0);
}

// ---------------------------------------------------------------------------
// k_prep: one kernel, 4 disjoint block ranges.
//  A [0,567):      pd repack -> ws_pdt[kc][col][40] bf16 (pose;shape;template)
//  B [567,799):    pose_feature+betas+1 -> ws_pfb[b][232] bf16
//  C [799,1069):   lbs weights -> ws_wb[v][40] bf16 (v<6912)
//  D [1069,1645):  J_regressor partial reductions -> ws_jsp (8 seg x 72 x 11)
// ---------------------------------------------------------------------------
__global__ __launch_bounds__(256) void k_prep(const float* __restrict__ pd,
                                              const float* __restrict__ sd,
                                              const float* __restrict__ vtm,
                                              const float* __restrict__ Jr,
                                              const float* __restrict__ bpose,
                                              const float* __restrict__ betas,
                                              const float* __restrict__ w,
                                              unsigned short* __restrict__ ws_pdt,
                                              unsigned short* __restrict__ ws_pfb,
                                              unsigned short* __restrict__ ws_wb,
                                              float* __restrict__ ws_jsp)
{
    int blk = blockIdx.x;
    if (blk < 567) {
        int t = blk * 256 + threadIdx.x;           // 0..145151
        int kc = t / NCOL;
        int col = t - kc * NCOL;
        bool cok = col < N3;
        unsigned short vals[40];
        #pragma unroll
        for (int kk = 0; kk < 32; kk++) {
            int gk = kc * 32 + kk;
            float val = 0.f;
            if (cok) {
                if (gk < PB)             val = pd[(size_t)gk * N3 + col];
                else if (gk < PB + 10)   val = sd[(size_t)col * NBETA + (gk - PB)];
                else if (gk == PB + 10)  val = vtm[col];
            }
            vals[kk] = f2bf(val);
        }
        #pragma unroll
        for (int kk = 32; kk < 40; kk++) vals[kk] = 0;
        uint4* dst = (uint4*)(ws_pdt + (size_t)t * 40);
        #pragma unroll
        for (int q = 0; q < 5; q++) {
            uint4 u;
            u.x = vals[q*8+0] | ((unsigned)vals[q*8+1] << 16);
            u.y = vals[q*8+2] | ((unsigned)vals[q*8+3] << 16);
            u.z = vals[q*8+4] | ((unsigned)vals[q*8+5] << 16);
            u.w = vals[q*8+6] | ((unsigned)vals[q*8+7] << 16);
            dst[q] = u;
        }
    } else if (blk < 799) {
        int e0 = (blk - 567) * 1024 + threadIdx.x * 4;   // 232*1024 total
        unsigned short v4[4];
        #pragma unroll
        for (int r = 0; r < 4; r++) {
            int e = e0 + r;
            int b = e / 232, k = e - b * 232;
            float x = 0.f;
            if (k < PB) {
                x = bpose[(size_t)b * PB + k];
                int k9 = k % 9;
                if (k9 == 0 || k9 == 4 || k9 == 8) x -= 1.f;
            } else if (k < PB + 10) {
                x = betas[b * NBETA + (k - PB)];
            } else if (k == PB + 10) {
                x = 1.f;
            }
            v4[r] = f2bf(x);
        }
        uint2 u;
        u.x = v4[0] | ((unsigned)v4[1] << 16);
        u.y = v4[2] | ((unsigned)v4[3] << 16);
        *(uint2*)(ws_pfb + e0) = u;
    } else if (blk < 1069) {
        int e0 = (blk - 799) * 1024 + threadIdx.x * 4;   // 6912*40 total
        unsigned short v4[4];
        #pragma unroll
        for (int r = 0; r < 4; r++) {
            int e = e0 + r;
            int v = e / 40, j = e - v * 40;
            float val = (j < 24 && v < NV) ? w[(size_t)v * 24 + j] : 0.f;
            v4[r] = f2bf(val);
        }
        uint2 u;
        u.x = v4[0] | ((unsigned)v4[1] << 16);
        u.y = v4[2] | ((unsigned)v4[3] << 16);
        *(uint2*)(ws_wb + e0) = u;
    } else {
        int b2 = blk - 1069;           // 0..575
        int jc = b2 >> 3;              // 0..71
        int seg = b2 & 7;              // 0..7
        int j = jc / 3, c = jc % 3;
        int v0 = seg * 862;
        int v1 = v0 + 862; if (v1 > NV) v1 = NV;

        float acc[11];
        #pragma unroll
        for (int l = 0; l < 11; l++) acc[l] = 0.f;

        for (int v = v0 + threadIdx.x; v < v1; v += 256) {
            float r = Jr[j * NV + v];
            acc[10] += r * vtm[v * 3 + c];
            const float* s = sd + (size_t)(v * 3 + c) * NBETA;
            #pragma unroll
            for (int l = 0; l < NBETA; l++) acc[l] += r * s[l];
        }

        __shared__ float red[4][11];
        int lane = threadIdx.x & 63, wv = threadIdx.x >> 6;
        #pragma unroll
        for (int l = 0; l < 11; l++) {
            float x = acc[l];
            x += __shfl_down(x, 32, 64);
            x += __shfl_down(x, 16, 64);
            x += __shfl_down(x, 8, 64);
            x += __shfl_down(x, 4, 64);
            x += __shfl_down(x, 2, 64);
            x += __shfl_down(x, 1, 64);
            if (lane == 0) red[wv][l] = x;
        }
        __syncthreads();
        if (threadIdx.x == 0) {
            #pragma unroll
            for (int l = 0; l < 11; l++)
                ws_jsp[((size_t)seg * 72 + jc) * 11 + l]
                    = red[0][l] + red[1][l] + red[2][l] + red[3][l];
        }
    }
}

// ---------------------------------------------------------------------------
// k_chain: 64 blocks x 256 threads, 16 batches/block (16 lanes per batch).
// Sums js partials, joints + kinematic chain; emits bf16 ArT[b][12][40] + pj.
// ---------------------------------------------------------------------------
__global__ __launch_bounds__(256) void k_chain(const float* __restrict__ betas,
                                               const float* __restrict__ grot,
                                               const float* __restrict__ bpose,
                                               const float* __restrict__ ws_jsp,
                                               unsigned short* __restrict__ ws_artb,
                                               float* __restrict__ pj)
{
    __shared__ float js_s[72 * 11];
    __shared__ float jt[16][72];
    __shared__ float tl[16][288];
    __shared__ float am[16][288];
    int tid = threadIdx.x;

    for (int e = tid; e < 72 * 11; e += 256) {
        float s = 0.f;
        #pragma unroll
        for (int seg = 0; seg < 8; seg++)
            s += ws_jsp[(size_t)seg * 792 + e];
        js_s[e] = s;
    }
    __syncthreads();

    int lb = tid >> 4;              // 0..15
    int e  = tid & 15;              // 0..15
    int b  = blockIdx.x * 16 + lb;

    for (int idx = e; idx < 72; idx += 16) {
        float acc = js_s[idx * 11 + 10];
        const float* be = betas + b * NBETA;
        #pragma unroll
        for (int l = 0; l < NBETA; l++) acc += be[l] * js_s[idx * 11 + l];
        jt[lb][idx] = acc;
    }
    __syncthreads();

    for (int idx = e; idx < 288; idx += 16) {
        int j = idx / 12, e12 = idx % 12, m = e12 >> 2, n = e12 & 3;
        float val;
        if (n < 3) {
            val = (j == 0) ? grot[(size_t)b * 9 + m * 3 + n]
                           : bpose[((size_t)b * 23 + (j - 1)) * 9 + m * 3 + n];
        } else {
            val = jt[lb][j * 3 + m];
            if (j > 0) val -= jt[lb][c_par[j] * 3 + m];
        }
        tl[lb][idx] = val;
    }
    __syncthreads();

    if (e < 12) am[lb][e] = tl[lb][e];
    for (int i = 1; i < 24; i++) {
        __syncthreads();
        if (e < 12) {
            int p = c_par[i];
            int m = e >> 2, n = e & 3;
            float val = am[lb][p*12 + m*4 + 0] * tl[lb][i*12 + 0 + n]
                      + am[lb][p*12 + m*4 + 1] * tl[lb][i*12 + 4 + n]
                      + am[lb][p*12 + m*4 + 2] * tl[lb][i*12 + 8 + n];
            if (n == 3) val += am[lb][p*12 + m*4 + 3];
            am[lb][i*12 + e] = val;
        }
    }
    __syncthreads();

    for (int idx = e; idx < 72; idx += 16) {
        int j = idx / 3, m = idx % 3;
        pj[(size_t)b * 72 + idx] = am[lb][j*12 + m*4 + 3];
    }
    // ArT[b][col=m*4+n][j'] bf16, j' 0..39 (24..39 zero)
    for (int idx = e; idx < 480; idx += 16) {
        int col = idx / 40, j = idx - col * 40;
        float val = 0.f;
        if (j < 24) {
            int m = col >> 2, n = col & 3;
            if (n < 3) {
                val = am[lb][j*12 + col];
            } else {
                val = am[lb][j*12 + m*4 + 3]
                    - am[lb][j*12 + m*4 + 0] * jt[lb][j*3 + 0]
                    - am[lb][j*12 + m*4 + 1] * jt[lb][j*3 + 1]
                    - am[lb][j*12 + m*4 + 2] * jt[lb][j*3 + 2];
            }
        }
        ws_artb[(size_t)b * 480 + idx] = f2bf(val);
    }
}

// ---------------------------------------------------------------------------
// k_vert, round 7: persistent-ish blocks. Grid (32 bb, 27) — each block
// sweeps 4 consecutive vb tiles for one bb. Amortizes block startup, pfb DMA
// (once per block, not per vb), and chains the depth-1 b-frag prefetch ACROSS
// the vb seam: at kc==6 the prefetch target is (vb+1, kc=0), so those loads
// fly during the whole phase 2 of the current vb.
// Per vb: 2 barriers (pre-scatter: prev phase-2 disp reads done; post-scatter).
// LDS 40,448 B -> 4 blocks/CU. XCD swizzle bijective (864 = 8*108).
// ---------------------------------------------------------------------------
__global__ __launch_bounds__(256, 4) void k_vert(const unsigned short* __restrict__ ws_pdt,
                                                 const unsigned short* __restrict__ ws_pfb,
                                                 const unsigned short* __restrict__ ws_wb,
                                                 const unsigned short* __restrict__ ws_artb,
                                                 float* __restrict__ out)
{
    // XCD-partition swizzle: lin%8 = XCD; each XCD owns a contiguous g range
    // (bb fastest within it -> pdt slices + artb stay L2-resident).
    const int lin = blockIdx.x + 32 * blockIdx.y;   // 0..863
    const int xcd = lin & 7;
    const int loc = lin >> 3;                        // 0..107
    const int g_id = xcd * 108 + loc;
    const int bb  = g_id & 31;                       // 0..31
    const int vb0 = (g_id >> 5) * 4;                 // 0,4,...,104

    const int tid = threadIdx.x;
    const int wv = tid >> 6;
    const int lane = tid & 63;
    const int r16 = lane & 15;
    const int half8 = (lane >> 4) * 8;

    __shared__ __align__(16) unsigned char smem[40448];
    float*          disp_l = (float*)smem;                    // [32][196] = 25,088 B
    unsigned short* pfb_l  = (unsigned short*)(smem + 25088); // 15,360 B (14,848 used)

    // ---- DMA pfb slice for bb into LDS (once per block).
    {
        const unsigned short* srcF = ws_pfb + (size_t)(bb * BT) * 232;
        for (int i = wv; i < 14; i += 4)
            dma16((const char*)srcF + i * 1024 + lane * 16, (char*)pfb_l + i * 1024);
        if (wv == 2 && lane < 32)      // tail: bytes 14336..14848
            dma16((const char*)srcF + 14 * 1024 + lane * 16, (char*)pfb_l + 14 * 1024);
    }

    // ---- b-frag pipeline base: + vb*7680 selects the vb tile, + kc*NCOL*40
    // the K chunk. Prologue: (vb0, kc=0).
    const unsigned short* pdt_base = ws_pdt + ((size_t)wv * 48 + r16) * 40 + half8;
    {
        const unsigned short* p0 = pdt_base + (size_t)vb0 * 7680;
        // loads issued before the barrier; they overlap the DMA drain
        // (prologue b regs declared below)
    }
    bf16x8 b0 = *(const bf16x8*)(pdt_base + (size_t)vb0 * 7680);
    bf16x8 b1 = *(const bf16x8*)(pdt_base + (size_t)vb0 * 7680 + 640);
    bf16x8 b2 = *(const bf16x8*)(pdt_base + (size_t)vb0 * 7680 + 1280);

    // phase-2 lane-constant decode: artcol = 16t + 4gq + r -> q = 4t+gq.
    const int gq = lane >> 4;
    int bl[3], mm[3];
    #pragma unroll
    for (int t = 0; t < 3; t++) {
        int q = 4 * t + gq;                   // 0..11
        bl[t] = (q * 11) >> 5;                // q/3 for q in [0,12)
        mm[t] = q - 3 * bl[t];
    }
    const unsigned short* pArt0 = ws_artb + (size_t)(bb * BT) * 480 + (size_t)r16 * 40 + half8;

    __syncthreads();      // pfb DMA landed

    for (int v4 = 0; v4 < 4; v4++) {
        const int vb = vb0 + v4;
        const unsigned short* pB = pdt_base + (size_t)vb * 7680;

        f32x4 acc[2][3];
        #pragma unroll
        for (int mt = 0; mt < 2; mt++)
            #pragma unroll
            for (int t = 0; t < 3; t++)
                acc[mt][t] = (f32x4){0.f, 0.f, 0.f, 0.f};

        // ---- phase 1: K loop, depth-1 prefetch; at kc==6 prefetch (vb+1,kc0)
        #pragma unroll
        for (int kc = 0; kc < NCHUNK; kc++) {
            bf16x8 a0 = *(const bf16x8*)(pfb_l + r16 * 232 + kc * 32 + half8);
            bf16x8 a1 = *(const bf16x8*)(pfb_l + (16 + r16) * 232 + kc * 32 + half8);
            bf16x8 b0n, b1n, b2n;
            const bool havenext = (kc < NCHUNK - 1) || (v4 < 3);
            if (havenext) {
                const unsigned short* pn = (kc < NCHUNK - 1)
                    ? pB + (size_t)(kc + 1) * NCOL * 40     // next K chunk
                    : pB + 7680;                            // next vb, kc=0
                b0n = *(const bf16x8*)(pn);
                b1n = *(const bf16x8*)(pn + 640);
                b2n = *(const bf16x8*)(pn + 1280);
            }
            acc[0][0] = __builtin_amdgcn_mfma_f32_16x16x32_bf16(a0, b0, acc[0][0], 0, 0, 0);
            acc[1][0] = __builtin_amdgcn_mfma_f32_16x16x32_bf16(a1, b0, acc[1][0], 0, 0, 0);
            acc[0][1] = __builtin_amdgcn_mfma_f32_16x16x32_bf16(a0, b1, acc[0][1], 0, 0, 0);
            acc[1][1] = __builtin_amdgcn_mfma_f32_16x16x32_bf16(a1, b1, acc[1][1], 0, 0, 0);
            acc[0][2] = __builtin_amdgcn_mfma_f32_16x16x32_bf16(a0, b2, acc[0][2], 0, 0, 0);
            acc[1][2] = __builtin_amdgcn_mfma_f32_16x16x32_bf16(a1, b2, acc[1][2], 0, 0, 0);
            if (havenext) { b0 = b0n; b1 = b1n; b2 = b2n; }
        }

        // ---- scatter v_posed into disp_l. Barrier first: previous vb's
        // phase-2 disp reads must be done (no-op cost on v4==0).
        __syncthreads();
        #pragma unroll
        for (int mt = 0; mt < 2; mt++) {
            #pragma unroll
            for (int t = 0; t < 3; t++) {
                int col = wv * 48 + t * 16 + r16;
                int brow = mt * 16 + (lane >> 4) * 4;
                #pragma unroll
                for (int r = 0; r < 4; r++)
                    disp_l[(brow + r) * 196 + col] = acc[mt][t][r];
            }
        }
        __syncthreads();      // disp complete

        // ---- phase 2: wave wv owns subs {wv, wv+4}, all 4 vert-groups.
        // Meanwhile the (vb+1) b-frag loads are in flight.
        bf16x8 aw[4];
        #pragma unroll
        for (int vg = 0; vg < 4; vg++)
            aw[vg] = *(const bf16x8*)(ws_wb + (size_t)(vb * 64 + vg * 16 + r16) * 40 + half8);

        const unsigned short* pc = pArt0 + (size_t)wv * 1920;   // 4 batches * 480
        bf16x8 c0 = *(const bf16x8*)(pc);
        bf16x8 c1 = *(const bf16x8*)(pc + 640);
        bf16x8 c2 = *(const bf16x8*)(pc + 1280);

        #pragma unroll
        for (int h = 0; h < 2; h++) {
            const int sub = wv + h * 4;
            bf16x8 c0n, c1n, c2n;
            if (h == 0) {
                const unsigned short* pn = pArt0 + (size_t)(wv + 4) * 1920;
                c0n = *(const bf16x8*)(pn);
                c1n = *(const bf16x8*)(pn + 640);
                c2n = *(const bf16x8*)(pn + 1280);
            }
            #pragma unroll
            for (int vg = 0; vg < 4; vg++) {
                f32x4 z = (f32x4){0.f, 0.f, 0.f, 0.f};
                f32x4 t0 = __builtin_amdgcn_mfma_f32_16x16x32_bf16(c0, aw[vg], z, 0, 0, 0);
                f32x4 t1 = __builtin_amdgcn_mfma_f32_16x16x32_bf16(c1, aw[vg], z, 0, 0, 0);
                f32x4 t2 = __builtin_amdgcn_mfma_f32_16x16x32_bf16(c2, aw[vg], z, 0, 0, 0);

                const int v16 = vg * 16 + r16;           // vert within block
                const int vg_glob = vb * 64 + v16;       // global vert
                #pragma unroll
                for (int t = 0; t < 3; t++) {
                    f32x4 tt = (t == 0) ? t0 : (t == 1) ? t1 : t2;
                    int row = sub * 4 + bl[t];
                    const float* d = disp_l + row * 196 + v16 * 3;
                    float x = d[0], y = d[1], zz = d[2];
                    float p = tt[0] * x + tt[1] * y + tt[2] * zz + tt[3];
                    if (vg_glob < NV)
                        out[(size_t)(bb * BT + row) * N3 + (size_t)vg_glob * 3 + mm[t]] = p;
                }
            }
            if (h == 0) { c0 = c0n; c1 = c1n; c2 = c2n; }
        }
    }
}

// ---------------------------------------------------------------------------
extern "C" void kernel_launch(void* const* d_in, const int* in_sizes, int n_in,
                              void* d_out, int out_size, void* d_ws, size_t ws_size,
                              hipStream_t stream) {
    const float* betas = (const float*)d_in[0];
    const float* grot  = (const float*)d_in[1];
    const float* bpose = (const float*)d_in[2];
    const float* vtm   = (const float*)d_in[3];
    const float* sd    = (const float*)d_in[4];
    const float* pd    = (const float*)d_in[5];
    const float* Jr    = (const float*)d_in[6];
    const float* w     = (const float*)d_in[7];
    float* out = (float*)d_out;

    char* ws = (char*)d_ws;
    unsigned short* ws_pdt  = (unsigned short*)(ws);              // 11,612,160 B
    unsigned short* ws_pfb  = (unsigned short*)(ws + 11612160);   //    475,136 B
    unsigned short* ws_wb   = (unsigned short*)(ws + 12087296);   //    552,960 B
    float*          ws_jsp  = (float*)         (ws + 12640256);   //     25,344 B
    unsigned short* ws_artb = (unsigned short*)(ws + 12665600);   //    983,040 B

    k_prep<<<1645, 256, 0, stream>>>(pd, sd, vtm, Jr, bpose, betas, w,
                                     ws_pdt, ws_pfb, ws_wb, ws_jsp);
    k_chain<<<BN / 16, 256, 0, stream>>>(betas, grot, bpose, ws_jsp, ws_artb,
                                         out + (size_t)BN * N3);
    k_vert<<<dim3(32, 27), 256, 0, stream>>>(ws_pdt, ws_pfb, ws_wb, ws_artb, out);
}

// Round 8
// 171.404 us; speedup vs baseline: 1.0279x; 1.0279x over previous
//
#include <hip/hip_runtime.h>

#define BN 1024
#define NV 6890
#define NBETA 10
#define PB 207            // pose basis = 9*(J-1)
#define N3 20670          // NV*3
#define NCOL 20736        // 108*192 padded GEMM columns
#define NCHUNK 7          // K = 224 = 207 pose + 10 betas + 1 template + 6 zero
#define BT 32             // batches per k_vert block

typedef __bf16 bf16x8 __attribute__((ext_vector_type(8)));
typedef float  f32x4  __attribute__((ext_vector_type(4)));

__device__ __constant__ int c_par[24] = {-1,0,0,0,1,2,3,4,5,6,7,8,9,9,9,12,13,14,16,17,18,19,20,21};

__device__ inline unsigned short f2bf(float f) {
    unsigned u = __float_as_uint(f);
    u += 0x7fff + ((u >> 16) & 1);          // RNE
    return (unsigned short)(u >> 16);
}

__device__ inline void dma16(const void* g, void* l) {
    __builtin_amdgcn_global_load_lds(
        (const __attribute__((address_space(1))) unsigned int*)g,
        (__attribute__((address_space(3))) unsigned int*)l, 16, 0, 0);
}

// ---------------------------------------------------------------------------
// k_prep: one kernel, 4 disjoint block ranges.
//  A [0,567):      pd repack -> ws_pdt[kc][col][40] bf16 (pose;shape;template)
//  B [567,799):    pose_feature+betas+1 -> ws_pfb[b][232] bf16
//  C [799,1069):   lbs weights -> ws_wb[v][40] bf16 (v<6912)
//  D [1069,1645):  J_regressor partial reductions -> ws_jsp (8 seg x 72 x 11)
// ---------------------------------------------------------------------------
__global__ __launch_bounds__(256) void k_prep(const float* __restrict__ pd,
                                              const float* __restrict__ sd,
                                              const float* __restrict__ vtm,
                                              const float* __restrict__ Jr,
                                              const float* __restrict__ bpose,
                                              const float* __restrict__ betas,
                                              const float* __restrict__ w,
                                              unsigned short* __restrict__ ws_pdt,
                                              unsigned short* __restrict__ ws_pfb,
                                              unsigned short* __restrict__ ws_wb,
                                              float* __restrict__ ws_jsp)
{
    int blk = blockIdx.x;
    if (blk < 567) {
        int t = blk * 256 + threadIdx.x;           // 0..145151
        int kc = t / NCOL;
        int col = t - kc * NCOL;
        bool cok = col < N3;
        unsigned short vals[40];
        #pragma unroll
        for (int kk = 0; kk < 32; kk++) {
            int gk = kc * 32 + kk;
            float val = 0.f;
            if (cok) {
                if (gk < PB)             val = pd[(size_t)gk * N3 + col];
                else if (gk < PB + 10)   val = sd[(size_t)col * NBETA + (gk - PB)];
                else if (gk == PB + 10)  val = vtm[col];
            }
            vals[kk] = f2bf(val);
        }
        #pragma unroll
        for (int kk = 32; kk < 40; kk++) vals[kk] = 0;
        uint4* dst = (uint4*)(ws_pdt + (size_t)t * 40);
        #pragma unroll
        for (int q = 0; q < 5; q++) {
            uint4 u;
            u.x = vals[q*8+0] | ((unsigned)vals[q*8+1] << 16);
            u.y = vals[q*8+2] | ((unsigned)vals[q*8+3] << 16);
            u.z = vals[q*8+4] | ((unsigned)vals[q*8+5] << 16);
            u.w = vals[q*8+6] | ((unsigned)vals[q*8+7] << 16);
            dst[q] = u;
        }
    } else if (blk < 799) {
        int e0 = (blk - 567) * 1024 + threadIdx.x * 4;   // 232*1024 total
        unsigned short v4[4];
        #pragma unroll
        for (int r = 0; r < 4; r++) {
            int e = e0 + r;
            int b = e / 232, k = e - b * 232;
            float x = 0.f;
            if (k < PB) {
                x = bpose[(size_t)b * PB + k];
                int k9 = k % 9;
                if (k9 == 0 || k9 == 4 || k9 == 8) x -= 1.f;
            } else if (k < PB + 10) {
                x = betas[b * NBETA + (k - PB)];
            } else if (k == PB + 10) {
                x = 1.f;
            }
            v4[r] = f2bf(x);
        }
        uint2 u;
        u.x = v4[0] | ((unsigned)v4[1] << 16);
        u.y = v4[2] | ((unsigned)v4[3] << 16);
        *(uint2*)(ws_pfb + e0) = u;
    } else if (blk < 1069) {
        int e0 = (blk - 799) * 1024 + threadIdx.x * 4;   // 6912*40 total
        unsigned short v4[4];
        #pragma unroll
        for (int r = 0; r < 4; r++) {
            int e = e0 + r;
            int v = e / 40, j = e - v * 40;
            float val = (j < 24 && v < NV) ? w[(size_t)v * 24 + j] : 0.f;
            v4[r] = f2bf(val);
        }
        uint2 u;
        u.x = v4[0] | ((unsigned)v4[1] << 16);
        u.y = v4[2] | ((unsigned)v4[3] << 16);
        *(uint2*)(ws_wb + e0) = u;
    } else {
        int b2 = blk - 1069;           // 0..575
        int jc = b2 >> 3;              // 0..71
        int seg = b2 & 7;              // 0..7
        int j = jc / 3, c = jc % 3;
        int v0 = seg * 862;
        int v1 = v0 + 862; if (v1 > NV) v1 = NV;

        float acc[11];
        #pragma unroll
        for (int l = 0; l < 11; l++) acc[l] = 0.f;

        for (int v = v0 + threadIdx.x; v < v1; v += 256) {
            float r = Jr[j * NV + v];
            acc[10] += r * vtm[v * 3 + c];
            const float* s = sd + (size_t)(v * 3 + c) * NBETA;
            #pragma unroll
            for (int l = 0; l < NBETA; l++) acc[l] += r * s[l];
        }

        __shared__ float red[4][11];
        int lane = threadIdx.x & 63, wv = threadIdx.x >> 6;
        #pragma unroll
        for (int l = 0; l < 11; l++) {
            float x = acc[l];
            x += __shfl_down(x, 32, 64);
            x += __shfl_down(x, 16, 64);
            x += __shfl_down(x, 8, 64);
            x += __shfl_down(x, 4, 64);
            x += __shfl_down(x, 2, 64);
            x += __shfl_down(x, 1, 64);
            if (lane == 0) red[wv][l] = x;
        }
        __syncthreads();
        if (threadIdx.x == 0) {
            #pragma unroll
            for (int l = 0; l < 11; l++)
                ws_jsp[((size_t)seg * 72 + jc) * 11 + l]
                    = red[0][l] + red[1][l] + red[2][l] + red[3][l];
        }
    }
}

// ---------------------------------------------------------------------------
// k_chain: 64 blocks x 256 threads, 16 batches/block (16 lanes per batch).
// Sums js partials, joints + kinematic chain; emits bf16 ArT[b][12][40] + pj.
// ---------------------------------------------------------------------------
__global__ __launch_bounds__(256) void k_chain(const float* __restrict__ betas,
                                               const float* __restrict__ grot,
                                               const float* __restrict__ bpose,
                                               const float* __restrict__ ws_jsp,
                                               unsigned short* __restrict__ ws_artb,
                                               float* __restrict__ pj)
{
    __shared__ float js_s[72 * 11];
    __shared__ float jt[16][72];
    __shared__ float tl[16][288];
    __shared__ float am[16][288];
    int tid = threadIdx.x;

    for (int e = tid; e < 72 * 11; e += 256) {
        float s = 0.f;
        #pragma unroll
        for (int seg = 0; seg < 8; seg++)
            s += ws_jsp[(size_t)seg * 792 + e];
        js_s[e] = s;
    }
    __syncthreads();

    int lb = tid >> 4;              // 0..15
    int e  = tid & 15;              // 0..15
    int b  = blockIdx.x * 16 + lb;

    for (int idx = e; idx < 72; idx += 16) {
        float acc = js_s[idx * 11 + 10];
        const float* be = betas + b * NBETA;
        #pragma unroll
        for (int l = 0; l < NBETA; l++) acc += be[l] * js_s[idx * 11 + l];
        jt[lb][idx] = acc;
    }
    __syncthreads();

    for (int idx = e; idx < 288; idx += 16) {
        int j = idx / 12, e12 = idx % 12, m = e12 >> 2, n = e12 & 3;
        float val;
        if (n < 3) {
            val = (j == 0) ? grot[(size_t)b * 9 + m * 3 + n]
                           : bpose[((size_t)b * 23 + (j - 1)) * 9 + m * 3 + n];
        } else {
            val = jt[lb][j * 3 + m];
            if (j > 0) val -= jt[lb][c_par[j] * 3 + m];
        }
        tl[lb][idx] = val;
    }
    __syncthreads();

    if (e < 12) am[lb][e] = tl[lb][e];
    for (int i = 1; i < 24; i++) {
        __syncthreads();
        if (e < 12) {
            int p = c_par[i];
            int m = e >> 2, n = e & 3;
            float val = am[lb][p*12 + m*4 + 0] * tl[lb][i*12 + 0 + n]
                      + am[lb][p*12 + m*4 + 1] * tl[lb][i*12 + 4 + n]
                      + am[lb][p*12 + m*4 + 2] * tl[lb][i*12 + 8 + n];
            if (n == 3) val += am[lb][p*12 + m*4 + 3];
            am[lb][i*12 + e] = val;
        }
    }
    __syncthreads();

    for (int idx = e; idx < 72; idx += 16) {
        int j = idx / 3, m = idx % 3;
        pj[(size_t)b * 72 + idx] = am[lb][j*12 + m*4 + 3];
    }
    // ArT[b][col=m*4+n][j'] bf16, j' 0..39 (24..39 zero)
    for (int idx = e; idx < 480; idx += 16) {
        int col = idx / 40, j = idx - col * 40;
        float val = 0.f;
        if (j < 24) {
            int m = col >> 2, n = col & 3;
            if (n < 3) {
                val = am[lb][j*12 + col];
            } else {
                val = am[lb][j*12 + m*4 + 3]
                    - am[lb][j*12 + m*4 + 0] * jt[lb][j*3 + 0]
                    - am[lb][j*12 + m*4 + 1] * jt[lb][j*3 + 1]
                    - am[lb][j*12 + m*4 + 2] * jt[lb][j*3 + 2];
            }
        }
        ws_artb[(size_t)b * 480 + idx] = f2bf(val);
    }
}

// ---------------------------------------------------------------------------
// k_vert, round 8: r6 structure (grid 32x108, best measured) + coalesced
// output epilogue. Phase 2 writes transformed p back into disp_l at the cell
// it consumed (reads buffered into regs first -> wave-lockstep makes it
// race-free; (h,vg) iterations touch disjoint cells), then one barrier and a
// block-wide float2 copy disp_l -> out (768 B contiguous rows; 12 coalesced
// store instrs/thread replace 24 scattered scalar stores).
// LDS 40,448 B -> 4 blocks/CU. 3 barriers total.
// ---------------------------------------------------------------------------
__global__ __launch_bounds__(256, 4) void k_vert(const unsigned short* __restrict__ ws_pdt,
                                                 const unsigned short* __restrict__ ws_pfb,
                                                 const unsigned short* __restrict__ ws_wb,
                                                 const unsigned short* __restrict__ ws_artb,
                                                 float* __restrict__ out)
{
    // XCD-partition swizzle (bijective on [0,3456)): lin%8 = XCD id.
    const int lin = blockIdx.x + 32 * blockIdx.y;   // 0..3455
    const int xcd = lin & 7;
    const int loc = lin >> 3;                        // 0..431
    const int g_id = xcd * 432 + loc;
    const int bb = g_id & 31;                        // 0..31
    const int vb = g_id >> 5;                        // 0..107

    const int tid = threadIdx.x;
    const int wv = tid >> 6;
    const int lane = tid & 63;
    const int r16 = lane & 15;
    const int half8 = (lane >> 4) * 8;

    __shared__ __align__(16) unsigned char smem[40448];
    float*          disp_l = (float*)smem;                    // [32][196] = 25,088 B
    unsigned short* pfb_l  = (unsigned short*)(smem + 25088); // 15,360 B (14,848 used)

    // ---- DMA pfb slice for bb into LDS.
    {
        const unsigned short* srcF = ws_pfb + (size_t)(bb * BT) * 232;
        for (int i = wv; i < 14; i += 4)
            dma16((const char*)srcF + i * 1024 + lane * 16, (char*)pfb_l + i * 1024);
        if (wv == 2 && lane < 32)      // tail: bytes 14336..14848
            dma16((const char*)srcF + 14 * 1024 + lane * 16, (char*)pfb_l + 14 * 1024);
    }

    // ---- phase-1 b-frags: direct global, depth-1 pipeline
    const unsigned short* pB0 = ws_pdt + ((size_t)vb * 192 + wv * 48 + r16) * 40 + half8;
    bf16x8 b0 = *(const bf16x8*)(pB0);
    bf16x8 b1 = *(const bf16x8*)(pB0 + 640);    // +16 rows * 40
    bf16x8 b2 = *(const bf16x8*)(pB0 + 1280);   // +32 rows * 40

    f32x4 acc[2][3];
    #pragma unroll
    for (int mt = 0; mt < 2; mt++)
        #pragma unroll
        for (int t = 0; t < 3; t++)
            acc[mt][t] = (f32x4){0.f, 0.f, 0.f, 0.f};

    __syncthreads();      // pfb DMA landed

    #pragma unroll
    for (int kc = 0; kc < NCHUNK; kc++) {
        bf16x8 a0 = *(const bf16x8*)(pfb_l + r16 * 232 + kc * 32 + half8);
        bf16x8 a1 = *(const bf16x8*)(pfb_l + (16 + r16) * 232 + kc * 32 + half8);
        bf16x8 b0n, b1n, b2n;
        if (kc < NCHUNK - 1) {
            const unsigned short* pn = pB0 + (size_t)(kc + 1) * NCOL * 40;
            b0n = *(const bf16x8*)(pn);
            b1n = *(const bf16x8*)(pn + 640);
            b2n = *(const bf16x8*)(pn + 1280);
        }
        acc[0][0] = __builtin_amdgcn_mfma_f32_16x16x32_bf16(a0, b0, acc[0][0], 0, 0, 0);
        acc[1][0] = __builtin_amdgcn_mfma_f32_16x16x32_bf16(a1, b0, acc[1][0], 0, 0, 0);
        acc[0][1] = __builtin_amdgcn_mfma_f32_16x16x32_bf16(a0, b1, acc[0][1], 0, 0, 0);
        acc[1][1] = __builtin_amdgcn_mfma_f32_16x16x32_bf16(a1, b1, acc[1][1], 0, 0, 0);
        acc[0][2] = __builtin_amdgcn_mfma_f32_16x16x32_bf16(a0, b2, acc[0][2], 0, 0, 0);
        acc[1][2] = __builtin_amdgcn_mfma_f32_16x16x32_bf16(a1, b2, acc[1][2], 0, 0, 0);
        if (kc < NCHUNK - 1) { b0 = b0n; b1 = b1n; b2 = b2n; }
    }

    // ---- scatter v_posed into disp_l
    #pragma unroll
    for (int mt = 0; mt < 2; mt++) {
        #pragma unroll
        for (int t = 0; t < 3; t++) {
            int col = wv * 48 + t * 16 + r16;
            int brow = mt * 16 + (lane >> 4) * 4;
            #pragma unroll
            for (int r = 0; r < 4; r++)
                disp_l[(brow + r) * 196 + col] = acc[mt][t][r];
        }
    }
    __syncthreads();      // disp complete

    // ---- phase 2: wave wv owns subs {wv, wv+4}, all 4 vert-groups.
    const int gq = lane >> 4;
    int bl[3], mm[3];
    #pragma unroll
    for (int t = 0; t < 3; t++) {
        int q = 4 * t + gq;                   // 0..11
        bl[t] = (q * 11) >> 5;                // q/3 for q in [0,12)
        mm[t] = q - 3 * bl[t];
    }

    bf16x8 aw[4];
    #pragma unroll
    for (int vg = 0; vg < 4; vg++)
        aw[vg] = *(const bf16x8*)(ws_wb + (size_t)(vb * 64 + vg * 16 + r16) * 40 + half8);

    const unsigned short* pArt0 = ws_artb + (size_t)(bb * BT) * 480 + (size_t)r16 * 40 + half8;

    const unsigned short* pc = pArt0 + (size_t)wv * 1920;   // 4 batches * 480
    bf16x8 c0 = *(const bf16x8*)(pc);
    bf16x8 c1 = *(const bf16x8*)(pc + 640);
    bf16x8 c2 = *(const bf16x8*)(pc + 1280);

    #pragma unroll
    for (int h = 0; h < 2; h++) {
        const int sub = wv + h * 4;
        bf16x8 c0n, c1n, c2n;
        if (h == 0) {
            const unsigned short* pn = pArt0 + (size_t)(wv + 4) * 1920;
            c0n = *(const bf16x8*)(pn);
            c1n = *(const bf16x8*)(pn + 640);
            c2n = *(const bf16x8*)(pn + 1280);
        }
        #pragma unroll
        for (int vg = 0; vg < 4; vg++) {
            f32x4 z = (f32x4){0.f, 0.f, 0.f, 0.f};
            f32x4 t0 = __builtin_amdgcn_mfma_f32_16x16x32_bf16(c0, aw[vg], z, 0, 0, 0);
            f32x4 t1 = __builtin_amdgcn_mfma_f32_16x16x32_bf16(c1, aw[vg], z, 0, 0, 0);
            f32x4 t2 = __builtin_amdgcn_mfma_f32_16x16x32_bf16(c2, aw[vg], z, 0, 0, 0);

            const int v16 = vg * 16 + r16;           // vert within block
            // Buffer ALL reads of this (h,vg) before ANY writeback: the
            // cells written below are exactly cells read here (by other
            // lanes of this wave); wave lockstep + program order = safe.
            float xyz[3][3];
            #pragma unroll
            for (int t = 0; t < 3; t++) {
                const float* d = disp_l + (sub * 4 + bl[t]) * 196 + v16 * 3;
                xyz[t][0] = d[0]; xyz[t][1] = d[1]; xyz[t][2] = d[2];
            }
            #pragma unroll
            for (int t = 0; t < 3; t++) {
                f32x4 tt = (t == 0) ? t0 : (t == 1) ? t1 : t2;
                float p = tt[0] * xyz[t][0] + tt[1] * xyz[t][1]
                        + tt[2] * xyz[t][2] + tt[3];
                disp_l[(sub * 4 + bl[t]) * 196 + v16 * 3 + mm[t]] = p;
            }
        }
        if (h == 0) { c0 = c0n; c1 = c1n; c2 = c2n; }
    }
    __syncthreads();      // all writebacks done

    // ---- coalesced copy disp_l -> out: 32 rows x 192 floats (float2 because
    // odd rows of out are only 8-mod-16 aligned). 3072 float2 / 256 threads.
    #pragma unroll
    for (int j = 0; j < 12; j++) {
        int i = tid + j * 256;
        int row = i / 96;                 // 96 float2 per row
        int c2  = i - row * 96;
        int gcol = vb * 192 + c2 * 2;
        if (gcol < N3) {
            float2 v = *(const float2*)(disp_l + row * 196 + c2 * 2);
            *(float2*)(out + (size_t)(bb * BT + row) * N3 + gcol) = v;
        }
    }
}

// ---------------------------------------------------------------------------
extern "C" void kernel_launch(void* const* d_in, const int* in_sizes, int n_in,
                              void* d_out, int out_size, void* d_ws, size_t ws_size,
                              hipStream_t stream) {
    const float* betas = (const float*)d_in[0];
    const float* grot  = (const float*)d_in[1];
    const float* bpose = (const float*)d_in[2];
    const float* vtm   = (const float*)d_in[3];
    const float* sd    = (const float*)d_in[4];
    const float* pd    = (const float*)d_in[5];
    const float* Jr    = (const float*)d_in[6];
    const float* w     = (const float*)d_in[7];
    float* out = (float*)d_out;

    char* ws = (char*)d_ws;
    unsigned short* ws_pdt  = (unsigned short*)(ws);              // 11,612,160 B
    unsigned short* ws_pfb  = (unsigned short*)(ws + 11612160);   //    475,136 B
    unsigned short* ws_wb   = (unsigned short*)(ws + 12087296);   //    552,960 B
    float*          ws_jsp  = (float*)         (ws + 12640256);   //     25,344 B
    unsigned short* ws_artb = (unsigned short*)(ws + 12665600);   //    983,040 B

    k_prep<<<1645, 256, 0, stream>>>(pd, sd, vtm, Jr, bpose, betas, w,
                                     ws_pdt, ws_pfb, ws_wb, ws_jsp);
    k_chain<<<BN / 16, 256, 0, stream>>>(betas, grot, bpose, ws_jsp, ws_artb,
                                         out + (size_t)BN * N3);
    k_vert<<<dim3(32, 108), 256, 0, stream>>>(ws_pdt, ws_pfb, ws_wb, ws_artb, out);
}

// Round 9
// 167.488 us; speedup vs baseline: 1.0519x; 1.0234x over previous
//
#include <hip/hip_runtime.h>

#define BN 1024
#define NV 6890
#define NBETA 10
#define PB 207            // pose basis = 9*(J-1)
#define N3 20670          // NV*3
#define NCOL 20736        // 108*192 padded GEMM columns
#define NCHUNK 7          // K = 224 = 207 pose + 10 betas + 1 template + 6 zero
#define BT 32             // batches per k_vert block

typedef __bf16 bf16x8 __attribute__((ext_vector_type(8)));
typedef float  f32x4  __attribute__((ext_vector_type(4)));

__device__ __constant__ int c_par[24] = {-1,0,0,0,1,2,3,4,5,6,7,8,9,9,9,12,13,14,16,17,18,19,20,21};

__device__ inline unsigned short f2bf(float f) {
    unsigned u = __float_as_uint(f);
    u += 0x7fff + ((u >> 16) & 1);          // RNE
    return (unsigned short)(u >> 16);
}

__device__ inline void dma16(const void* g, void* l) {
    __builtin_amdgcn_global_load_lds(
        (const __attribute__((address_space(1))) unsigned int*)g,
        (__attribute__((address_space(3))) unsigned int*)l, 16, 0, 0);
}

// ---------------------------------------------------------------------------
// k_prep: one kernel, 4 disjoint block ranges.
//  A [0,567):      pd repack -> ws_pdt[kc][col][40] bf16 (pose;shape;template)
//  B [567,799):    pose_feature+betas+1 -> ws_pfb[b][232] bf16
//  C [799,1069):   lbs weights -> ws_wb[v][40] bf16 (v<6912)
//  D [1069,1645):  J_regressor partial reductions -> ws_jsp (8 seg x 72 x 11)
// ---------------------------------------------------------------------------
__global__ __launch_bounds__(256) void k_prep(const float* __restrict__ pd,
                                              const float* __restrict__ sd,
                                              const float* __restrict__ vtm,
                                              const float* __restrict__ Jr,
                                              const float* __restrict__ bpose,
                                              const float* __restrict__ betas,
                                              const float* __restrict__ w,
                                              unsigned short* __restrict__ ws_pdt,
                                              unsigned short* __restrict__ ws_pfb,
                                              unsigned short* __restrict__ ws_wb,
                                              float* __restrict__ ws_jsp)
{
    int blk = blockIdx.x;
    if (blk < 567) {
        int t = blk * 256 + threadIdx.x;           // 0..145151
        int kc = t / NCOL;
        int col = t - kc * NCOL;
        bool cok = col < N3;
        unsigned short vals[40];
        #pragma unroll
        for (int kk = 0; kk < 32; kk++) {
            int gk = kc * 32 + kk;
            float val = 0.f;
            if (cok) {
                if (gk < PB)             val = pd[(size_t)gk * N3 + col];
                else if (gk < PB + 10)   val = sd[(size_t)col * NBETA + (gk - PB)];
                else if (gk == PB + 10)  val = vtm[col];
            }
            vals[kk] = f2bf(val);
        }
        #pragma unroll
        for (int kk = 32; kk < 40; kk++) vals[kk] = 0;
        uint4* dst = (uint4*)(ws_pdt + (size_t)t * 40);
        #pragma unroll
        for (int q = 0; q < 5; q++) {
            uint4 u;
            u.x = vals[q*8+0] | ((unsigned)vals[q*8+1] << 16);
            u.y = vals[q*8+2] | ((unsigned)vals[q*8+3] << 16);
            u.z = vals[q*8+4] | ((unsigned)vals[q*8+5] << 16);
            u.w = vals[q*8+6] | ((unsigned)vals[q*8+7] << 16);
            dst[q] = u;
        }
    } else if (blk < 799) {
        int e0 = (blk - 567) * 1024 + threadIdx.x * 4;   // 232*1024 total
        unsigned short v4[4];
        #pragma unroll
        for (int r = 0; r < 4; r++) {
            int e = e0 + r;
            int b = e / 232, k = e - b * 232;
            float x = 0.f;
            if (k < PB) {
                x = bpose[(size_t)b * PB + k];
                int k9 = k % 9;
                if (k9 == 0 || k9 == 4 || k9 == 8) x -= 1.f;
            } else if (k < PB + 10) {
                x = betas[b * NBETA + (k - PB)];
            } else if (k == PB + 10) {
                x = 1.f;
            }
            v4[r] = f2bf(x);
        }
        uint2 u;
        u.x = v4[0] | ((unsigned)v4[1] << 16);
        u.y = v4[2] | ((unsigned)v4[3] << 16);
        *(uint2*)(ws_pfb + e0) = u;
    } else if (blk < 1069) {
        int e0 = (blk - 799) * 1024 + threadIdx.x * 4;   // 6912*40 total
        unsigned short v4[4];
        #pragma unroll
        for (int r = 0; r < 4; r++) {
            int e = e0 + r;
            int v = e / 40, j = e - v * 40;
            float val = (j < 24 && v < NV) ? w[(size_t)v * 24 + j] : 0.f;
            v4[r] = f2bf(val);
        }
        uint2 u;
        u.x = v4[0] | ((unsigned)v4[1] << 16);
        u.y = v4[2] | ((unsigned)v4[3] << 16);
        *(uint2*)(ws_wb + e0) = u;
    } else {
        int b2 = blk - 1069;           // 0..575
        int jc = b2 >> 3;              // 0..71
        int seg = b2 & 7;              // 0..7
        int j = jc / 3, c = jc % 3;
        int v0 = seg * 862;
        int v1 = v0 + 862; if (v1 > NV) v1 = NV;

        float acc[11];
        #pragma unroll
        for (int l = 0; l < 11; l++) acc[l] = 0.f;

        for (int v = v0 + threadIdx.x; v < v1; v += 256) {
            float r = Jr[j * NV + v];
            acc[10] += r * vtm[v * 3 + c];
            const float* s = sd + (size_t)(v * 3 + c) * NBETA;
            #pragma unroll
            for (int l = 0; l < NBETA; l++) acc[l] += r * s[l];
        }

        __shared__ float red[4][11];
        int lane = threadIdx.x & 63, wv = threadIdx.x >> 6;
        #pragma unroll
        for (int l = 0; l < 11; l++) {
            float x = acc[l];
            x += __shfl_down(x, 32, 64);
            x += __shfl_down(x, 16, 64);
            x += __shfl_down(x, 8, 64);
            x += __shfl_down(x, 4, 64);
            x += __shfl_down(x, 2, 64);
            x += __shfl_down(x, 1, 64);
            if (lane == 0) red[wv][l] = x;
        }
        __syncthreads();
        if (threadIdx.x == 0) {
            #pragma unroll
            for (int l = 0; l < 11; l++)
                ws_jsp[((size_t)seg * 72 + jc) * 11 + l]
                    = red[0][l] + red[1][l] + red[2][l] + red[3][l];
        }
    }
}

// ---------------------------------------------------------------------------
// k_chain: 64 blocks x 256 threads, 16 batches/block (16 lanes per batch).
// Sums js partials, joints + kinematic chain; emits bf16 ArT[b][12][40] + pj.
// ---------------------------------------------------------------------------
__global__ __launch_bounds__(256) void k_chain(const float* __restrict__ betas,
                                               const float* __restrict__ grot,
                                               const float* __restrict__ bpose,
                                               const float* __restrict__ ws_jsp,
                                               unsigned short* __restrict__ ws_artb,
                                               float* __restrict__ pj)
{
    __shared__ float js_s[72 * 11];
    __shared__ float jt[16][72];
    __shared__ float tl[16][288];
    __shared__ float am[16][288];
    int tid = threadIdx.x;

    for (int e = tid; e < 72 * 11; e += 256) {
        float s = 0.f;
        #pragma unroll
        for (int seg = 0; seg < 8; seg++)
            s += ws_jsp[(size_t)seg * 792 + e];
        js_s[e] = s;
    }
    __syncthreads();

    int lb = tid >> 4;              // 0..15
    int e  = tid & 15;              // 0..15
    int b  = blockIdx.x * 16 + lb;

    for (int idx = e; idx < 72; idx += 16) {
        float acc = js_s[idx * 11 + 10];
        const float* be = betas + b * NBETA;
        #pragma unroll
        for (int l = 0; l < NBETA; l++) acc += be[l] * js_s[idx * 11 + l];
        jt[lb][idx] = acc;
    }
    __syncthreads();

    for (int idx = e; idx < 288; idx += 16) {
        int j = idx / 12, e12 = idx % 12, m = e12 >> 2, n = e12 & 3;
        float val;
        if (n < 3) {
            val = (j == 0) ? grot[(size_t)b * 9 + m * 3 + n]
                           : bpose[((size_t)b * 23 + (j - 1)) * 9 + m * 3 + n];
        } else {
            val = jt[lb][j * 3 + m];
            if (j > 0) val -= jt[lb][c_par[j] * 3 + m];
        }
        tl[lb][idx] = val;
    }
    __syncthreads();

    if (e < 12) am[lb][e] = tl[lb][e];
    for (int i = 1; i < 24; i++) {
        __syncthreads();
        if (e < 12) {
            int p = c_par[i];
            int m = e >> 2, n = e & 3;
            float val = am[lb][p*12 + m*4 + 0] * tl[lb][i*12 + 0 + n]
                      + am[lb][p*12 + m*4 + 1] * tl[lb][i*12 + 4 + n]
                      + am[lb][p*12 + m*4 + 2] * tl[lb][i*12 + 8 + n];
            if (n == 3) val += am[lb][p*12 + m*4 + 3];
            am[lb][i*12 + e] = val;
        }
    }
    __syncthreads();

    for (int idx = e; idx < 72; idx += 16) {
        int j = idx / 3, m = idx % 3;
        pj[(size_t)b * 72 + idx] = am[lb][j*12 + m*4 + 3];
    }
    // ArT[b][col=m*4+n][j'] bf16, j' 0..39 (24..39 zero)
    for (int idx = e; idx < 480; idx += 16) {
        int col = idx / 40, j = idx - col * 40;
        float val = 0.f;
        if (j < 24) {
            int m = col >> 2, n = col & 3;
            if (n < 3) {
                val = am[lb][j*12 + col];
            } else {
                val = am[lb][j*12 + m*4 + 3]
                    - am[lb][j*12 + m*4 + 0] * jt[lb][j*3 + 0]
                    - am[lb][j*12 + m*4 + 1] * jt[lb][j*3 + 1]
                    - am[lb][j*12 + m*4 + 2] * jt[lb][j*3 + 2];
            }
        }
        ws_artb[(size_t)b * 480 + idx] = f2bf(val);
    }
}

// ---------------------------------------------------------------------------
// k_vert, round 9: DEPTH-2 phase-1 pipeline + issue-early phase-2 loads.
// Theory: iteration time = max(work ~60-100cy, L2-latency/depth). Depth-1
// gave ~250cy/iter (waves 75% stalled, MfmaUtil 10%); depth-2 targets
// ~125cy/iter. Phase-2 c/aw loads hoisted before the disp scatter+barrier
// so their latency hides under it. Rest identical to r8 (grid 32x108,
// XCD-partition swizzle, LDS-writeback + coalesced float2 output).
// ---------------------------------------------------------------------------
__global__ __launch_bounds__(256, 4) void k_vert(const unsigned short* __restrict__ ws_pdt,
                                                 const unsigned short* __restrict__ ws_pfb,
                                                 const unsigned short* __restrict__ ws_wb,
                                                 const unsigned short* __restrict__ ws_artb,
                                                 float* __restrict__ out)
{
    // XCD-partition swizzle (bijective on [0,3456)): lin%8 = XCD id.
    const int lin = blockIdx.x + 32 * blockIdx.y;   // 0..3455
    const int xcd = lin & 7;
    const int loc = lin >> 3;                        // 0..431
    const int g_id = xcd * 432 + loc;
    const int bb = g_id & 31;                        // 0..31
    const int vb = g_id >> 5;                        // 0..107

    const int tid = threadIdx.x;
    const int wv = tid >> 6;
    const int lane = tid & 63;
    const int r16 = lane & 15;
    const int half8 = (lane >> 4) * 8;

    __shared__ __align__(16) unsigned char smem[40448];
    float*          disp_l = (float*)smem;                    // [32][196] = 25,088 B
    unsigned short* pfb_l  = (unsigned short*)(smem + 25088); // 15,360 B (14,848 used)

    // ---- DMA pfb slice for bb into LDS.
    {
        const unsigned short* srcF = ws_pfb + (size_t)(bb * BT) * 232;
        for (int i = wv; i < 14; i += 4)
            dma16((const char*)srcF + i * 1024 + lane * 16, (char*)pfb_l + i * 1024);
        if (wv == 2 && lane < 32)      // tail: bytes 14336..14848
            dma16((const char*)srcF + 14 * 1024 + lane * 16, (char*)pfb_l + 14 * 1024);
    }

    // ---- phase-1 b-frags: depth-2 pipeline. Two sets in flight; prologue
    // issues chunks 0 and 1 (overlapping the pfb DMA drain).
    const unsigned short* pB0 = ws_pdt + ((size_t)vb * 192 + wv * 48 + r16) * 40 + half8;
    bf16x8 B[2][3];
    B[0][0] = *(const bf16x8*)(pB0);
    B[0][1] = *(const bf16x8*)(pB0 + 640);
    B[0][2] = *(const bf16x8*)(pB0 + 1280);
    {
        const unsigned short* p1 = pB0 + (size_t)NCOL * 40;
        B[1][0] = *(const bf16x8*)(p1);
        B[1][1] = *(const bf16x8*)(p1 + 640);
        B[1][2] = *(const bf16x8*)(p1 + 1280);
    }

    f32x4 acc[2][3];
    #pragma unroll
    for (int mt = 0; mt < 2; mt++)
        #pragma unroll
        for (int t = 0; t < 3; t++)
            acc[mt][t] = (f32x4){0.f, 0.f, 0.f, 0.f};

    __syncthreads();      // pfb DMA landed

    #pragma unroll
    for (int kc = 0; kc < NCHUNK; kc++) {        // fully unrolled: kc&1 static
        bf16x8 a0 = *(const bf16x8*)(pfb_l + r16 * 232 + kc * 32 + half8);
        bf16x8 a1 = *(const bf16x8*)(pfb_l + (16 + r16) * 232 + kc * 32 + half8);
        bf16x8 b0n, b1n, b2n;
        if (kc + 2 < NCHUNK) {                   // prefetch 2 chunks ahead
            const unsigned short* pn = pB0 + (size_t)(kc + 2) * NCOL * 40;
            b0n = *(const bf16x8*)(pn);
            b1n = *(const bf16x8*)(pn + 640);
            b2n = *(const bf16x8*)(pn + 1280);
        }
        const int s = kc & 1;
        acc[0][0] = __builtin_amdgcn_mfma_f32_16x16x32_bf16(a0, B[s][0], acc[0][0], 0, 0, 0);
        acc[1][0] = __builtin_amdgcn_mfma_f32_16x16x32_bf16(a1, B[s][0], acc[1][0], 0, 0, 0);
        acc[0][1] = __builtin_amdgcn_mfma_f32_16x16x32_bf16(a0, B[s][1], acc[0][1], 0, 0, 0);
        acc[1][1] = __builtin_amdgcn_mfma_f32_16x16x32_bf16(a1, B[s][1], acc[1][1], 0, 0, 0);
        acc[0][2] = __builtin_amdgcn_mfma_f32_16x16x32_bf16(a0, B[s][2], acc[0][2], 0, 0, 0);
        acc[1][2] = __builtin_amdgcn_mfma_f32_16x16x32_bf16(a1, B[s][2], acc[1][2], 0, 0, 0);
        if (kc + 2 < NCHUNK) { B[s][0] = b0n; B[s][1] = b1n; B[s][2] = b2n; }
    }

    // ---- issue-early: phase-2 operand loads BEFORE the scatter+barrier,
    // so their ~250cy L2 latency hides under it.
    bf16x8 aw[4];
    #pragma unroll
    for (int vg = 0; vg < 4; vg++)
        aw[vg] = *(const bf16x8*)(ws_wb + (size_t)(vb * 64 + vg * 16 + r16) * 40 + half8);

    const unsigned short* pArt0 = ws_artb + (size_t)(bb * BT) * 480 + (size_t)r16 * 40 + half8;
    bf16x8 C0[3], C1[3];
    {
        const unsigned short* p0 = pArt0 + (size_t)wv * 1920;        // sub = wv
        const unsigned short* p1 = pArt0 + (size_t)(wv + 4) * 1920;  // sub = wv+4
        C0[0] = *(const bf16x8*)(p0);
        C0[1] = *(const bf16x8*)(p0 + 640);
        C0[2] = *(const bf16x8*)(p0 + 1280);
        C1[0] = *(const bf16x8*)(p1);
        C1[1] = *(const bf16x8*)(p1 + 640);
        C1[2] = *(const bf16x8*)(p1 + 1280);
    }

    // ---- scatter v_posed into disp_l
    #pragma unroll
    for (int mt = 0; mt < 2; mt++) {
        #pragma unroll
        for (int t = 0; t < 3; t++) {
            int col = wv * 48 + t * 16 + r16;
            int brow = mt * 16 + (lane >> 4) * 4;
            #pragma unroll
            for (int r = 0; r < 4; r++)
                disp_l[(brow + r) * 196 + col] = acc[mt][t][r];
        }
    }
    __syncthreads();      // disp complete

    // ---- phase 2: wave wv owns subs {wv, wv+4}, all 4 vert-groups.
    const int gq = lane >> 4;
    int bl[3], mm[3];
    #pragma unroll
    for (int t = 0; t < 3; t++) {
        int q = 4 * t + gq;                   // 0..11
        bl[t] = (q * 11) >> 5;                // q/3 for q in [0,12)
        mm[t] = q - 3 * bl[t];
    }

    #pragma unroll
    for (int h = 0; h < 2; h++) {             // static: h selects C0/C1
        const int sub = wv + h * 4;
        #pragma unroll
        for (int vg = 0; vg < 4; vg++) {
            f32x4 z = (f32x4){0.f, 0.f, 0.f, 0.f};
            f32x4 t0, t1, t2;
            if (h == 0) {
                t0 = __builtin_amdgcn_mfma_f32_16x16x32_bf16(C0[0], aw[vg], z, 0, 0, 0);
                t1 = __builtin_amdgcn_mfma_f32_16x16x32_bf16(C0[1], aw[vg], z, 0, 0, 0);
                t2 = __builtin_amdgcn_mfma_f32_16x16x32_bf16(C0[2], aw[vg], z, 0, 0, 0);
            } else {
                t0 = __builtin_amdgcn_mfma_f32_16x16x32_bf16(C1[0], aw[vg], z, 0, 0, 0);
                t1 = __builtin_amdgcn_mfma_f32_16x16x32_bf16(C1[1], aw[vg], z, 0, 0, 0);
                t2 = __builtin_amdgcn_mfma_f32_16x16x32_bf16(C1[2], aw[vg], z, 0, 0, 0);
            }

            const int v16 = vg * 16 + r16;           // vert within block
            // Buffer ALL reads of this (h,vg) before ANY writeback (wave
            // lockstep + program order make the in-place update race-free;
            // (h,vg) iterations touch disjoint cells).
            float xyz[3][3];
            #pragma unroll
            for (int t = 0; t < 3; t++) {
                const float* d = disp_l + (sub * 4 + bl[t]) * 196 + v16 * 3;
                xyz[t][0] = d[0]; xyz[t][1] = d[1]; xyz[t][2] = d[2];
            }
            #pragma unroll
            for (int t = 0; t < 3; t++) {
                f32x4 tt = (t == 0) ? t0 : (t == 1) ? t1 : t2;
                float p = tt[0] * xyz[t][0] + tt[1] * xyz[t][1]
                        + tt[2] * xyz[t][2] + tt[3];
                disp_l[(sub * 4 + bl[t]) * 196 + v16 * 3 + mm[t]] = p;
            }
        }
    }
    __syncthreads();      // all writebacks done

    // ---- coalesced copy disp_l -> out: 32 rows x 192 floats (float2 because
    // odd rows of out are only 8-mod-16 aligned). 3072 float2 / 256 threads.
    #pragma unroll
    for (int j = 0; j < 12; j++) {
        int i = tid + j * 256;
        int row = i / 96;                 // 96 float2 per row
        int c2  = i - row * 96;
        int gcol = vb * 192 + c2 * 2;
        if (gcol < N3) {
            float2 v = *(const float2*)(disp_l + row * 196 + c2 * 2);
            *(float2*)(out + (size_t)(bb * BT + row) * N3 + gcol) = v;
        }
    }
}

// ---------------------------------------------------------------------------
extern "C" void kernel_launch(void* const* d_in, const int* in_sizes, int n_in,
                              void* d_out, int out_size, void* d_ws, size_t ws_size,
                              hipStream_t stream) {
    const float* betas = (const float*)d_in[0];
    const float* grot  = (const float*)d_in[1];
    const float* bpose = (const float*)d_in[2];
    const float* vtm   = (const float*)d_in[3];
    const float* sd    = (const float*)d_in[4];
    const float* pd    = (const float*)d_in[5];
    const float* Jr    = (const float*)d_in[6];
    const float* w     = (const float*)d_in[7];
    float* out = (float*)d_out;

    char* ws = (char*)d_ws;
    unsigned short* ws_pdt  = (unsigned short*)(ws);              // 11,612,160 B
    unsigned short* ws_pfb  = (unsigned short*)(ws + 11612160);   //    475,136 B
    unsigned short* ws_wb   = (unsigned short*)(ws + 12087296);   //    552,960 B
    float*          ws_jsp  = (float*)         (ws + 12640256);   //     25,344 B
    unsigned short* ws_artb = (unsigned short*)(ws + 12665600);   //    983,040 B

    k_prep<<<1645, 256, 0, stream>>>(pd, sd, vtm, Jr, bpose, betas, w,
                                     ws_pdt, ws_pfb, ws_wb, ws_jsp);
    k_chain<<<BN / 16, 256, 0, stream>>>(betas, grot, bpose, ws_jsp, ws_artb,
                                         out + (size_t)BN * N3);
    k_vert<<<dim3(32, 108), 256, 0, stream>>>(ws_pdt, ws_pfb, ws_wb, ws_artb, out);
}

// Round 10
// 167.054 us; speedup vs baseline: 1.0546x; 1.0026x over previous
//
#include <hip/hip_runtime.h>

#define BN 1024
#define NV 6890
#define NBETA 10
#define PB 207            // pose basis = 9*(J-1)
#define N3 20670          // NV*3
#define NCOL 20736        // 108*192 padded GEMM columns
#define NCHUNK 7          // K = 224 = 207 pose + 10 betas + 1 template + 6 zero
#define BT 32             // batches per k_vert block

typedef __bf16 bf16x8 __attribute__((ext_vector_type(8)));
typedef float  f32x4  __attribute__((ext_vector_type(4)));

__device__ __constant__ int c_par[24] = {-1,0,0,0,1,2,3,4,5,6,7,8,9,9,9,12,13,14,16,17,18,19,20,21};

__device__ inline unsigned short f2bf(float f) {
    unsigned u = __float_as_uint(f);
    u += 0x7fff + ((u >> 16) & 1);          // RNE
    return (unsigned short)(u >> 16);
}

__device__ inline void dma16(const void* g, void* l) {
    __builtin_amdgcn_global_load_lds(
        (const __attribute__((address_space(1))) unsigned int*)g,
        (__attribute__((address_space(3))) unsigned int*)l, 16, 0, 0);
}

// ---------------------------------------------------------------------------
// k_prep: one kernel, 4 disjoint block ranges.
//  A [0,567):      pd repack -> ws_pdt[kc][col][40] bf16 (pose;shape;template)
//  B [567,799):    pose_feature+betas+1 -> ws_pfb[b][232] bf16
//  C [799,1069):   lbs weights -> ws_wb[v][40] bf16 (v<6912)
//  D [1069,1645):  J_regressor partial reductions -> ws_jsp (8 seg x 72 x 11)
// ---------------------------------------------------------------------------
__global__ __launch_bounds__(256) void k_prep(const float* __restrict__ pd,
                                              const float* __restrict__ sd,
                                              const float* __restrict__ vtm,
                                              const float* __restrict__ Jr,
                                              const float* __restrict__ bpose,
                                              const float* __restrict__ betas,
                                              const float* __restrict__ w,
                                              unsigned short* __restrict__ ws_pdt,
                                              unsigned short* __restrict__ ws_pfb,
                                              unsigned short* __restrict__ ws_wb,
                                              float* __restrict__ ws_jsp)
{
    int blk = blockIdx.x;
    if (blk < 567) {
        int t = blk * 256 + threadIdx.x;           // 0..145151
        int kc = t / NCOL;
        int col = t - kc * NCOL;
        bool cok = col < N3;
        unsigned short vals[40];
        #pragma unroll
        for (int kk = 0; kk < 32; kk++) {
            int gk = kc * 32 + kk;
            float val = 0.f;
            if (cok) {
                if (gk < PB)             val = pd[(size_t)gk * N3 + col];
                else if (gk < PB + 10)   val = sd[(size_t)col * NBETA + (gk - PB)];
                else if (gk == PB + 10)  val = vtm[col];
            }
            vals[kk] = f2bf(val);
        }
        #pragma unroll
        for (int kk = 32; kk < 40; kk++) vals[kk] = 0;
        uint4* dst = (uint4*)(ws_pdt + (size_t)t * 40);
        #pragma unroll
        for (int q = 0; q < 5; q++) {
            uint4 u;
            u.x = vals[q*8+0] | ((unsigned)vals[q*8+1] << 16);
            u.y = vals[q*8+2] | ((unsigned)vals[q*8+3] << 16);
            u.z = vals[q*8+4] | ((unsigned)vals[q*8+5] << 16);
            u.w = vals[q*8+6] | ((unsigned)vals[q*8+7] << 16);
            dst[q] = u;
        }
    } else if (blk < 799) {
        int e0 = (blk - 567) * 1024 + threadIdx.x * 4;   // 232*1024 total
        unsigned short v4[4];
        #pragma unroll
        for (int r = 0; r < 4; r++) {
            int e = e0 + r;
            int b = e / 232, k = e - b * 232;
            float x = 0.f;
            if (k < PB) {
                x = bpose[(size_t)b * PB + k];
                int k9 = k % 9;
                if (k9 == 0 || k9 == 4 || k9 == 8) x -= 1.f;
            } else if (k < PB + 10) {
                x = betas[b * NBETA + (k - PB)];
            } else if (k == PB + 10) {
                x = 1.f;
            }
            v4[r] = f2bf(x);
        }
        uint2 u;
        u.x = v4[0] | ((unsigned)v4[1] << 16);
        u.y = v4[2] | ((unsigned)v4[3] << 16);
        *(uint2*)(ws_pfb + e0) = u;
    } else if (blk < 1069) {
        int e0 = (blk - 799) * 1024 + threadIdx.x * 4;   // 6912*40 total
        unsigned short v4[4];
        #pragma unroll
        for (int r = 0; r < 4; r++) {
            int e = e0 + r;
            int v = e / 40, j = e - v * 40;
            float val = (j < 24 && v < NV) ? w[(size_t)v * 24 + j] : 0.f;
            v4[r] = f2bf(val);
        }
        uint2 u;
        u.x = v4[0] | ((unsigned)v4[1] << 16);
        u.y = v4[2] | ((unsigned)v4[3] << 16);
        *(uint2*)(ws_wb + e0) = u;
    } else {
        int b2 = blk - 1069;           // 0..575
        int jc = b2 >> 3;              // 0..71
        int seg = b2 & 7;              // 0..7
        int j = jc / 3, c = jc % 3;
        int v0 = seg * 862;
        int v1 = v0 + 862; if (v1 > NV) v1 = NV;

        float acc[11];
        #pragma unroll
        for (int l = 0; l < 11; l++) acc[l] = 0.f;

        for (int v = v0 + threadIdx.x; v < v1; v += 256) {
            float r = Jr[j * NV + v];
            acc[10] += r * vtm[v * 3 + c];
            const float* s = sd + (size_t)(v * 3 + c) * NBETA;
            #pragma unroll
            for (int l = 0; l < NBETA; l++) acc[l] += r * s[l];
        }

        __shared__ float red[4][11];
        int lane = threadIdx.x & 63, wv = threadIdx.x >> 6;
        #pragma unroll
        for (int l = 0; l < 11; l++) {
            float x = acc[l];
            x += __shfl_down(x, 32, 64);
            x += __shfl_down(x, 16, 64);
            x += __shfl_down(x, 8, 64);
            x += __shfl_down(x, 4, 64);
            x += __shfl_down(x, 2, 64);
            x += __shfl_down(x, 1, 64);
            if (lane == 0) red[wv][l] = x;
        }
        __syncthreads();
        if (threadIdx.x == 0) {
            #pragma unroll
            for (int l = 0; l < 11; l++)
                ws_jsp[((size_t)seg * 72 + jc) * 11 + l]
                    = red[0][l] + red[1][l] + red[2][l] + red[3][l];
        }
    }
}

// ---------------------------------------------------------------------------
// k_chain: 64 blocks x 256 threads, 16 batches/block (16 lanes per batch).
// Sums js partials, joints + kinematic chain; emits bf16 ArT[b][12][40] + pj.
// ---------------------------------------------------------------------------
__global__ __launch_bounds__(256) void k_chain(const float* __restrict__ betas,
                                               const float* __restrict__ grot,
                                               const float* __restrict__ bpose,
                                               const float* __restrict__ ws_jsp,
                                               unsigned short* __restrict__ ws_artb,
                                               float* __restrict__ pj)
{
    __shared__ float js_s[72 * 11];
    __shared__ float jt[16][72];
    __shared__ float tl[16][288];
    __shared__ float am[16][288];
    int tid = threadIdx.x;

    for (int e = tid; e < 72 * 11; e += 256) {
        float s = 0.f;
        #pragma unroll
        for (int seg = 0; seg < 8; seg++)
            s += ws_jsp[(size_t)seg * 792 + e];
        js_s[e] = s;
    }
    __syncthreads();

    int lb = tid >> 4;              // 0..15
    int e  = tid & 15;              // 0..15
    int b  = blockIdx.x * 16 + lb;

    for (int idx = e; idx < 72; idx += 16) {
        float acc = js_s[idx * 11 + 10];
        const float* be = betas + b * NBETA;
        #pragma unroll
        for (int l = 0; l < NBETA; l++) acc += be[l] * js_s[idx * 11 + l];
        jt[lb][idx] = acc;
    }
    __syncthreads();

    for (int idx = e; idx < 288; idx += 16) {
        int j = idx / 12, e12 = idx % 12, m = e12 >> 2, n = e12 & 3;
        float val;
        if (n < 3) {
            val = (j == 0) ? grot[(size_t)b * 9 + m * 3 + n]
                           : bpose[((size_t)b * 23 + (j - 1)) * 9 + m * 3 + n];
        } else {
            val = jt[lb][j * 3 + m];
            if (j > 0) val -= jt[lb][c_par[j] * 3 + m];
        }
        tl[lb][idx] = val;
    }
    __syncthreads();

    if (e < 12) am[lb][e] = tl[lb][e];
    for (int i = 1; i < 24; i++) {
        __syncthreads();
        if (e < 12) {
            int p = c_par[i];
            int m = e >> 2, n = e & 3;
            float val = am[lb][p*12 + m*4 + 0] * tl[lb][i*12 + 0 + n]
                      + am[lb][p*12 + m*4 + 1] * tl[lb][i*12 + 4 + n]
                      + am[lb][p*12 + m*4 + 2] * tl[lb][i*12 + 8 + n];
            if (n == 3) val += am[lb][p*12 + m*4 + 3];
            am[lb][i*12 + e] = val;
        }
    }
    __syncthreads();

    for (int idx = e; idx < 72; idx += 16) {
        int j = idx / 3, m = idx % 3;
        pj[(size_t)b * 72 + idx] = am[lb][j*12 + m*4 + 3];
    }
    // ArT[b][col=m*4+n][j'] bf16, j' 0..39 (24..39 zero)
    for (int idx = e; idx < 480; idx += 16) {
        int col = idx / 40, j = idx - col * 40;
        float val = 0.f;
        if (j < 24) {
            int m = col >> 2, n = col & 3;
            if (n < 3) {
                val = am[lb][j*12 + col];
            } else {
                val = am[lb][j*12 + m*4 + 3]
                    - am[lb][j*12 + m*4 + 0] * jt[lb][j*3 + 0]
                    - am[lb][j*12 + m*4 + 1] * jt[lb][j*3 + 1]
                    - am[lb][j*12 + m*4 + 2] * jt[lb][j*3 + 2];
            }
        }
        ws_artb[(size_t)b * 480 + idx] = f2bf(val);
    }
}

// ---------------------------------------------------------------------------
// k_vert, round 10: DEPTH-3 phase-1 pipeline (B[3][3], prefetch kc+3).
// r9's depth-2 validated the latency theory (-4 us); depth-3 targets the
// issue-bound floor (~83cy/iter). VGPR ~+12, still <=128 -> no wave loss.
// Everything else identical to r9 (grid 32x108, XCD-partition swizzle,
// pfb LDS staging, issue-early phase-2 loads, LDS-writeback + coalesced
// float2 output).
// ---------------------------------------------------------------------------
__global__ __launch_bounds__(256, 4) void k_vert(const unsigned short* __restrict__ ws_pdt,
                                                 const unsigned short* __restrict__ ws_pfb,
                                                 const unsigned short* __restrict__ ws_wb,
                                                 const unsigned short* __restrict__ ws_artb,
                                                 float* __restrict__ out)
{
    // XCD-partition swizzle (bijective on [0,3456)): lin%8 = XCD id.
    const int lin = blockIdx.x + 32 * blockIdx.y;   // 0..3455
    const int xcd = lin & 7;
    const int loc = lin >> 3;                        // 0..431
    const int g_id = xcd * 432 + loc;
    const int bb = g_id & 31;                        // 0..31
    const int vb = g_id >> 5;                        // 0..107

    const int tid = threadIdx.x;
    const int wv = tid >> 6;
    const int lane = tid & 63;
    const int r16 = lane & 15;
    const int half8 = (lane >> 4) * 8;

    __shared__ __align__(16) unsigned char smem[40448];
    float*          disp_l = (float*)smem;                    // [32][196] = 25,088 B
    unsigned short* pfb_l  = (unsigned short*)(smem + 25088); // 15,360 B (14,848 used)

    // ---- DMA pfb slice for bb into LDS.
    {
        const unsigned short* srcF = ws_pfb + (size_t)(bb * BT) * 232;
        for (int i = wv; i < 14; i += 4)
            dma16((const char*)srcF + i * 1024 + lane * 16, (char*)pfb_l + i * 1024);
        if (wv == 2 && lane < 32)      // tail: bytes 14336..14848
            dma16((const char*)srcF + 14 * 1024 + lane * 16, (char*)pfb_l + 14 * 1024);
    }

    // ---- phase-1 b-frags: depth-3 pipeline. Three sets in flight; prologue
    // issues chunks 0,1,2 (overlapping the pfb DMA drain).
    const unsigned short* pB0 = ws_pdt + ((size_t)vb * 192 + wv * 48 + r16) * 40 + half8;
    bf16x8 B[3][3];
    #pragma unroll
    for (int s = 0; s < 3; s++) {
        const unsigned short* p = pB0 + (size_t)s * NCOL * 40;
        B[s][0] = *(const bf16x8*)(p);
        B[s][1] = *(const bf16x8*)(p + 640);
        B[s][2] = *(const bf16x8*)(p + 1280);
    }

    f32x4 acc[2][3];
    #pragma unroll
    for (int mt = 0; mt < 2; mt++)
        #pragma unroll
        for (int t = 0; t < 3; t++)
            acc[mt][t] = (f32x4){0.f, 0.f, 0.f, 0.f};

    __syncthreads();      // pfb DMA landed

    #pragma unroll
    for (int kc = 0; kc < NCHUNK; kc++) {        // fully unrolled: kc%3 static
        bf16x8 a0 = *(const bf16x8*)(pfb_l + r16 * 232 + kc * 32 + half8);
        bf16x8 a1 = *(const bf16x8*)(pfb_l + (16 + r16) * 232 + kc * 32 + half8);
        bf16x8 b0n, b1n, b2n;
        if (kc + 3 < NCHUNK) {                   // prefetch 3 chunks ahead
            const unsigned short* pn = pB0 + (size_t)(kc + 3) * NCOL * 40;
            b0n = *(const bf16x8*)(pn);
            b1n = *(const bf16x8*)(pn + 640);
            b2n = *(const bf16x8*)(pn + 1280);
        }
        const int s = kc % 3;
        acc[0][0] = __builtin_amdgcn_mfma_f32_16x16x32_bf16(a0, B[s][0], acc[0][0], 0, 0, 0);
        acc[1][0] = __builtin_amdgcn_mfma_f32_16x16x32_bf16(a1, B[s][0], acc[1][0], 0, 0, 0);
        acc[0][1] = __builtin_amdgcn_mfma_f32_16x16x32_bf16(a0, B[s][1], acc[0][1], 0, 0, 0);
        acc[1][1] = __builtin_amdgcn_mfma_f32_16x16x32_bf16(a1, B[s][1], acc[1][1], 0, 0, 0);
        acc[0][2] = __builtin_amdgcn_mfma_f32_16x16x32_bf16(a0, B[s][2], acc[0][2], 0, 0, 0);
        acc[1][2] = __builtin_amdgcn_mfma_f32_16x16x32_bf16(a1, B[s][2], acc[1][2], 0, 0, 0);
        if (kc + 3 < NCHUNK) { B[s][0] = b0n; B[s][1] = b1n; B[s][2] = b2n; }
    }

    // ---- issue-early: phase-2 operand loads BEFORE the scatter+barrier,
    // so their ~250cy L2 latency hides under it.
    bf16x8 aw[4];
    #pragma unroll
    for (int vg = 0; vg < 4; vg++)
        aw[vg] = *(const bf16x8*)(ws_wb + (size_t)(vb * 64 + vg * 16 + r16) * 40 + half8);

    const unsigned short* pArt0 = ws_artb + (size_t)(bb * BT) * 480 + (size_t)r16 * 40 + half8;
    bf16x8 C0[3], C1[3];
    {
        const unsigned short* p0 = pArt0 + (size_t)wv * 1920;        // sub = wv
        const unsigned short* p1 = pArt0 + (size_t)(wv + 4) * 1920;  // sub = wv+4
        C0[0] = *(const bf16x8*)(p0);
        C0[1] = *(const bf16x8*)(p0 + 640);
        C0[2] = *(const bf16x8*)(p0 + 1280);
        C1[0] = *(const bf16x8*)(p1);
        C1[1] = *(const bf16x8*)(p1 + 640);
        C1[2] = *(const bf16x8*)(p1 + 1280);
    }

    // ---- scatter v_posed into disp_l
    #pragma unroll
    for (int mt = 0; mt < 2; mt++) {
        #pragma unroll
        for (int t = 0; t < 3; t++) {
            int col = wv * 48 + t * 16 + r16;
            int brow = mt * 16 + (lane >> 4) * 4;
            #pragma unroll
            for (int r = 0; r < 4; r++)
                disp_l[(brow + r) * 196 + col] = acc[mt][t][r];
        }
    }
    __syncthreads();      // disp complete

    // ---- phase 2: wave wv owns subs {wv, wv+4}, all 4 vert-groups.
    const int gq = lane >> 4;
    int bl[3], mm[3];
    #pragma unroll
    for (int t = 0; t < 3; t++) {
        int q = 4 * t + gq;                   // 0..11
        bl[t] = (q * 11) >> 5;                // q/3 for q in [0,12)
        mm[t] = q - 3 * bl[t];
    }

    #pragma unroll
    for (int h = 0; h < 2; h++) {             // static: h selects C0/C1
        const int sub = wv + h * 4;
        #pragma unroll
        for (int vg = 0; vg < 4; vg++) {
            f32x4 z = (f32x4){0.f, 0.f, 0.f, 0.f};
            f32x4 t0, t1, t2;
            if (h == 0) {
                t0 = __builtin_amdgcn_mfma_f32_16x16x32_bf16(C0[0], aw[vg], z, 0, 0, 0);
                t1 = __builtin_amdgcn_mfma_f32_16x16x32_bf16(C0[1], aw[vg], z, 0, 0, 0);
                t2 = __builtin_amdgcn_mfma_f32_16x16x32_bf16(C0[2], aw[vg], z, 0, 0, 0);
            } else {
                t0 = __builtin_amdgcn_mfma_f32_16x16x32_bf16(C1[0], aw[vg], z, 0, 0, 0);
                t1 = __builtin_amdgcn_mfma_f32_16x16x32_bf16(C1[1], aw[vg], z, 0, 0, 0);
                t2 = __builtin_amdgcn_mfma_f32_16x16x32_bf16(C1[2], aw[vg], z, 0, 0, 0);
            }

            const int v16 = vg * 16 + r16;           // vert within block
            // Buffer ALL reads of this (h,vg) before ANY writeback (wave
            // lockstep + program order make the in-place update race-free;
            // (h,vg) iterations touch disjoint cells).
            float xyz[3][3];
            #pragma unroll
            for (int t = 0; t < 3; t++) {
                const float* d = disp_l + (sub * 4 + bl[t]) * 196 + v16 * 3;
                xyz[t][0] = d[0]; xyz[t][1] = d[1]; xyz[t][2] = d[2];
            }
            #pragma unroll
            for (int t = 0; t < 3; t++) {
                f32x4 tt = (t == 0) ? t0 : (t == 1) ? t1 : t2;
                float p = tt[0] * xyz[t][0] + tt[1] * xyz[t][1]
                        + tt[2] * xyz[t][2] + tt[3];
                disp_l[(sub * 4 + bl[t]) * 196 + v16 * 3 + mm[t]] = p;
            }
        }
    }
    __syncthreads();      // all writebacks done

    // ---- coalesced copy disp_l -> out: 32 rows x 192 floats (float2 because
    // odd rows of out are only 8-mod-16 aligned). 3072 float2 / 256 threads.
    #pragma unroll
    for (int j = 0; j < 12; j++) {
        int i = tid + j * 256;
        int row = i / 96;                 // 96 float2 per row
        int c2  = i - row * 96;
        int gcol = vb * 192 + c2 * 2;
        if (gcol < N3) {
            float2 v = *(const float2*)(disp_l + row * 196 + c2 * 2);
            *(float2*)(out + (size_t)(bb * BT + row) * N3 + gcol) = v;
        }
    }
}

// ---------------------------------------------------------------------------
extern "C" void kernel_launch(void* const* d_in, const int* in_sizes, int n_in,
                              void* d_out, int out_size, void* d_ws, size_t ws_size,
                              hipStream_t stream) {
    const float* betas = (const float*)d_in[0];
    const float* grot  = (const float*)d_in[1];
    const float* bpose = (const float*)d_in[2];
    const float* vtm   = (const float*)d_in[3];
    const float* sd    = (const float*)d_in[4];
    const float* pd    = (const float*)d_in[5];
    const float* Jr    = (const float*)d_in[6];
    const float* w     = (const float*)d_in[7];
    float* out = (float*)d_out;

    char* ws = (char*)d_ws;
    unsigned short* ws_pdt  = (unsigned short*)(ws);              // 11,612,160 B
    unsigned short* ws_pfb  = (unsigned short*)(ws + 11612160);   //    475,136 B
    unsigned short* ws_wb   = (unsigned short*)(ws + 12087296);   //    552,960 B
    float*          ws_jsp  = (float*)         (ws + 12640256);   //     25,344 B
    unsigned short* ws_artb = (unsigned short*)(ws + 12665600);   //    983,040 B

    k_prep<<<1645, 256, 0, stream>>>(pd, sd, vtm, Jr, bpose, betas, w,
                                     ws_pdt, ws_pfb, ws_wb, ws_jsp);
    k_chain<<<BN / 16, 256, 0, stream>>>(betas, grot, bpose, ws_jsp, ws_artb,
                                         out + (size_t)BN * N3);
    k_vert<<<dim3(32, 108), 256, 0, stream>>>(ws_pdt, ws_pfb, ws_wb, ws_artb, out);
}